// Round 5
// baseline (404.615 us; speedup 1.0000x reference)
//
#include <hip/hip_runtime.h>
#include <math.h>

#define EMB 2048
#define NH 16
#define HD 128
#define BATCH 8
#define SEQ 16
#define KVLEN 4096
#define KSPLIT 8
#define MROWS (BATCH * SEQ) /* 128 */

__device__ __forceinline__ float dot4(float4 a, float4 b) {
  return a.x * b.x + a.y * b.y + a.z * b.z + a.w * b.w;
}

// ---------------------------------------------------------------------------
// fp32 GEMM: Ypart[r][d] = sum_{c in k-slice} X[r][c] * W[d][c].
// (unchanged from R3/R4 — working)
// ---------------------------------------------------------------------------
__global__ __launch_bounds__(256) void gemm_f32(
    const float* __restrict__ X, const float* __restrict__ W0,
    const float* __restrict__ W1, const float* __restrict__ W2,
    float* __restrict__ Yp) {
  const int z = blockIdx.z;
  const float* __restrict__ W = (z == 0) ? W0 : (z == 1) ? W1 : W2;
  const int kp = blockIdx.y;       // 0..7
  const int c0 = blockIdx.x * 64;  // col block
  const int k0 = kp * 256;         // k-slice start
  const int tid = threadIdx.x;
  const int lane = tid & 63;
  const int wid = tid >> 6;

  const int colg = lane & 15;
  const int rbase = wid * 32 + (lane >> 4) * 8;
  const int perm = lane & 7;

  __shared__ float wt[2][64 * 32];

  float acc[8][4];
#pragma unroll
  for (int i = 0; i < 8; ++i)
#pragma unroll
    for (int c = 0; c < 4; ++c) acc[i][c] = 0.f;

  const int sc0 = tid >> 3, sk = tid & 7;
  const int sc1 = 32 + sc0;
  const float* wsrc0 = &W[(size_t)(c0 + sc0) * EMB + k0 + sk * 4];
  const float* wsrc1 = &W[(size_t)(c0 + sc1) * EMB + k0 + sk * 4];
  const int wo0 = sc0 * 32 + 4 * (sk ^ ((sc0 >> 2) & 7));
  const int wo1 = sc1 * 32 + 4 * (sk ^ ((sc1 >> 2) & 7));

  const float* xbase = X + (size_t)rbase * EMB + k0;

  float4 s0 = *(const float4*)(wsrc0);
  float4 s1 = *(const float4*)(wsrc1);
  *(float4*)&wt[0][wo0] = s0;
  *(float4*)&wt[0][wo1] = s1;
  float4 n0 = *(const float4*)(wsrc0 + 32);
  float4 n1 = *(const float4*)(wsrc1 + 32);
  __syncthreads();

  for (int t = 0; t < 8; ++t) {
    const int buf = t & 1;
    const float* wb = &wt[buf][0];
    const int xoff = t * 32;
#pragma unroll
    for (int k4 = 0; k4 < 8; ++k4) {
      float4 xv[8];
#pragma unroll
      for (int i = 0; i < 8; ++i)
        xv[i] = *(const float4*)&xbase[(size_t)i * EMB + xoff + k4 * 4];
      float4 wv[4];
#pragma unroll
      for (int c = 0; c < 4; ++c)
        wv[c] = *(const float4*)&wb[(4 * colg + c) * 32 + 4 * (k4 ^ perm)];
#pragma unroll
      for (int i = 0; i < 8; ++i)
#pragma unroll
        for (int c = 0; c < 4; ++c)
          acc[i][c] = fmaf(xv[i].w, wv[c].w,
                      fmaf(xv[i].z, wv[c].z,
                      fmaf(xv[i].y, wv[c].y,
                      fmaf(xv[i].x, wv[c].x, acc[i][c]))));
    }
    if (t < 7) {
      *(float4*)&wt[buf ^ 1][wo0] = n0;
      *(float4*)&wt[buf ^ 1][wo1] = n1;
      if (t < 6) {
        n0 = *(const float4*)(wsrc0 + (t + 2) * 32);
        n1 = *(const float4*)(wsrc1 + (t + 2) * 32);
      }
    }
    __syncthreads();
  }

  float* yout = Yp + ((size_t)(z * 8 + kp) * MROWS + rbase) * EMB + c0 + colg * 4;
#pragma unroll
  for (int i = 0; i < 8; ++i)
    *(float4*)&yout[(size_t)i * EMB] =
        make_float4(acc[i][0], acc[i][1], acc[i][2], acc[i][3]);
}

// ---------------------------------------------------------------------------
// Sum 8 split-K parts per matrix; apply RoPE to q,k (z=0,1); v plain.
// ---------------------------------------------------------------------------
__global__ __launch_bounds__(256) void sum_qkv_rope_k(
    const float* __restrict__ parts, float* __restrict__ yq,
    float* __restrict__ yk, float* __restrict__ yv) {
  const int idx4 = blockIdx.x * 256 + threadIdx.x;
  const int idx = idx4 << 2;
  const int row = idx >> 11;
  const int col = idx & 2047;
  const float s = (float)(row & 15);
  const int hd = col & 127;
  const float a0 = s * powf(10000.0f, -(float)hd * (1.0f / 128.0f));
  const float a1 = s * powf(10000.0f, -(float)(hd + 2) * (1.0f / 128.0f));
  float sn0, cs0, sn1, cs1;
  sincosf(a0, &sn0, &cs0);
  sincosf(a1, &sn1, &cs1);
  const float4* p = (const float4*)parts;
  float* outs[3] = {yq, yk, yv};
#pragma unroll
  for (int z = 0; z < 3; ++z) {
    float4 v = make_float4(0.f, 0.f, 0.f, 0.f);
#pragma unroll
    for (int k = 0; k < 8; ++k) {
      float4 a = p[((size_t)(z * 8 + k)) * 65536 + idx4];
      v.x += a.x; v.y += a.y; v.z += a.z; v.w += a.w;
    }
    if (z < 2) {
      float4 r;
      r.x = v.x * cs0 - v.y * sn0;
      r.y = v.x * sn0 + v.y * cs0;
      r.z = v.z * cs1 - v.w * sn1;
      r.w = v.z * sn1 + v.w * cs1;
      v = r;
    }
    ((float4*)outs[z])[idx4] = v;
  }
}

// ---------------------------------------------------------------------------
// sum 8 split-K parts + bias -> final output
// ---------------------------------------------------------------------------
__global__ __launch_bounds__(256) void sum8_bias_k(const float* __restrict__ parts,
                                                   const float* __restrict__ bo,
                                                   float* __restrict__ out) {
  const size_t idx = (size_t)blockIdx.x * 256 + threadIdx.x;
  float4 s = *(const float4*)&bo[(idx << 2) & 2047];
  const float4* p = (const float4*)parts;
#pragma unroll
  for (int k = 0; k < 8; ++k) {
    float4 v = p[(size_t)k * 65536 + idx];
    s.x += v.x; s.y += v.y; s.z += v.z; s.w += v.w;
  }
  ((float4*)out)[idx] = s;
}

// ---------------------------------------------------------------------------
// Flash-decoding attention partial — LDS-FREE version.
// Grid (KSPLIT, NH, BATCH), 256 threads = 4 independent waves (no barriers).
// Wave = 4 q-rows. Lane = (kslot 0..7: keys kslot+8i, g 0..7: d-slice 16g..+15).
// K/V read per-lane as b128 straight from global: each chunk hits HBM once,
// L2 serves the 4x reuse across waves (tile is L2-resident). Q pre-scaled in
// registers. Scores reduced over g via shfl_xor(8,16,32); softmax in regs;
// acc[4][16] reduced over kslot at the end.
// ---------------------------------------------------------------------------
__global__ __launch_bounds__(256, 2) void attn_partial_k(
    const float* __restrict__ q, const float* __restrict__ knew,
    const float* __restrict__ vnew, const float* __restrict__ ck,
    const float* __restrict__ cv, const int* __restrict__ sp_ptr,
    float* __restrict__ po, float* __restrict__ pm, float* __restrict__ pl) {
  const int j = blockIdx.x, h = blockIdx.y, b = blockIdx.z;
  const int tid = threadIdx.x;
  const int wid = tid >> 6;   // wave: q rows 4wid..4wid+3
  const int lane = tid & 63;
  const int kslot = lane & 7;
  const int g = lane >> 3;
  const int sp = *sp_ptr;
  const int L = sp + SEQ;
  const int nTiles = (L + 63) >> 6;
  const int tA = (nTiles * j) >> 3;
  const int tB = (nTiles * (j + 1)) >> 3;

  const float qscale = 0.08838834764831845f;  // 1/sqrt(128)
  // Q in registers: 4 q-rows x 16-d slice, pre-scaled
  float4 Q[4][4];
  {
    const float* qb = q + (size_t)(b * SEQ + (wid << 2)) * EMB + h * HD + (g << 4);
#pragma unroll
    for (int qq = 0; qq < 4; ++qq)
#pragma unroll
      for (int c = 0; c < 4; ++c) {
        float4 v = *(const float4*)&qb[(size_t)qq * EMB + (c << 2)];
        v.x *= qscale; v.y *= qscale; v.z *= qscale; v.w *= qscale;
        Q[qq][c] = v;
      }
  }

  float acc[4][16];
#pragma unroll
  for (int qq = 0; qq < 4; ++qq)
#pragma unroll
    for (int d = 0; d < 16; ++d) acc[qq][d] = 0.f;
  float m[4] = {-1e30f, -1e30f, -1e30f, -1e30f};
  float l[4] = {0.f, 0.f, 0.f, 0.f};

  const size_t ckBase = (size_t)b * KVLEN * EMB + h * HD + (g << 4);
  const size_t knBase = (size_t)b * SEQ * EMB + h * HD + (g << 4);

  for (int t = tA; t < tB; ++t) {
    const int t0 = t << 6;
    float p8[4][8];
    // ---- scores: this lane's 8 keys x 4 q, 16-d partial dots ----
#pragma unroll 4
    for (int i = 0; i < 8; ++i) {
      const int gk = t0 + kslot + (i << 3);
      const int gkE = min(gk, L - 1);
      const float* kp = (gkE < sp) ? &ck[ckBase + (size_t)gkE * EMB]
                                   : &knew[knBase + (size_t)(gkE - sp) * EMB];
      const float4 K0 = ((const float4*)kp)[0];
      const float4 K1 = ((const float4*)kp)[1];
      const float4 K2 = ((const float4*)kp)[2];
      const float4 K3 = ((const float4*)kp)[3];
#pragma unroll
      for (int qq = 0; qq < 4; ++qq)
        p8[qq][i] = dot4(K0, Q[qq][0]) + dot4(K1, Q[qq][1]) +
                    dot4(K2, Q[qq][2]) + dot4(K3, Q[qq][3]);
    }
    // ---- reduce over g (lane bits 3..5), mask tail ----
#pragma unroll
    for (int qq = 0; qq < 4; ++qq)
#pragma unroll
      for (int i = 0; i < 8; ++i) {
        float v = p8[qq][i];
        v += __shfl_xor(v, 8);
        v += __shfl_xor(v, 16);
        v += __shfl_xor(v, 32);
        if (t0 + kslot + (i << 3) >= L) v = -3.0e38f;
        p8[qq][i] = v;
      }
    // ---- online softmax per q-row (reduce over kslot bits 0..2) ----
#pragma unroll
    for (int qq = 0; qq < 4; ++qq) {
      float tm = p8[qq][0];
#pragma unroll
      for (int i = 1; i < 8; ++i) tm = fmaxf(tm, p8[qq][i]);
      tm = fmaxf(tm, __shfl_xor(tm, 1));
      tm = fmaxf(tm, __shfl_xor(tm, 2));
      tm = fmaxf(tm, __shfl_xor(tm, 4));
      float mn = fmaxf(m[qq], tm);
      float sc = __expf(m[qq] - mn);
      float ls = 0.f;
#pragma unroll
      for (int i = 0; i < 8; ++i) {
        float pe = __expf(p8[qq][i] - mn);
        p8[qq][i] = pe;
        ls += pe;
      }
      ls += __shfl_xor(ls, 1);
      ls += __shfl_xor(ls, 2);
      ls += __shfl_xor(ls, 4);
      l[qq] = l[qq] * sc + ls;
      m[qq] = mn;
#pragma unroll
      for (int d = 0; d < 16; ++d) acc[qq][d] *= sc;
    }
    // ---- PV: same 8 keys, V 16-d slice, straight from global ----
#pragma unroll 4
    for (int i = 0; i < 8; ++i) {
      const int gk = t0 + kslot + (i << 3);
      const int gkE = min(gk, L - 1);
      const float* vp = (gkE < sp) ? &cv[ckBase + (size_t)gkE * EMB]
                                   : &vnew[knBase + (size_t)(gkE - sp) * EMB];
      const float4 V0 = ((const float4*)vp)[0];
      const float4 V1 = ((const float4*)vp)[1];
      const float4 V2 = ((const float4*)vp)[2];
      const float4 V3 = ((const float4*)vp)[3];
#pragma unroll
      for (int qq = 0; qq < 4; ++qq) {
        const float pv = p8[qq][i];
        acc[qq][0]  = fmaf(pv, V0.x, acc[qq][0]);
        acc[qq][1]  = fmaf(pv, V0.y, acc[qq][1]);
        acc[qq][2]  = fmaf(pv, V0.z, acc[qq][2]);
        acc[qq][3]  = fmaf(pv, V0.w, acc[qq][3]);
        acc[qq][4]  = fmaf(pv, V1.x, acc[qq][4]);
        acc[qq][5]  = fmaf(pv, V1.y, acc[qq][5]);
        acc[qq][6]  = fmaf(pv, V1.z, acc[qq][6]);
        acc[qq][7]  = fmaf(pv, V1.w, acc[qq][7]);
        acc[qq][8]  = fmaf(pv, V2.x, acc[qq][8]);
        acc[qq][9]  = fmaf(pv, V2.y, acc[qq][9]);
        acc[qq][10] = fmaf(pv, V2.z, acc[qq][10]);
        acc[qq][11] = fmaf(pv, V2.w, acc[qq][11]);
        acc[qq][12] = fmaf(pv, V3.x, acc[qq][12]);
        acc[qq][13] = fmaf(pv, V3.y, acc[qq][13]);
        acc[qq][14] = fmaf(pv, V3.z, acc[qq][14]);
        acc[qq][15] = fmaf(pv, V3.w, acc[qq][15]);
      }
    }
  }

  // ---- reduce acc over kslot lanes; write partials ----
#pragma unroll
  for (int qq = 0; qq < 4; ++qq)
#pragma unroll
    for (int d = 0; d < 16; ++d) {
      float v = acc[qq][d];
      v += __shfl_xor(v, 1);
      v += __shfl_xor(v, 2);
      v += __shfl_xor(v, 4);
      acc[qq][d] = v;
    }
  const size_t pair = (size_t)(b * NH + h);
  const size_t pb = (pair * KSPLIT + j) * SEQ + (wid << 2);
  if (kslot == 0) {
#pragma unroll
    for (int qq = 0; qq < 4; ++qq)
#pragma unroll
      for (int c = 0; c < 4; ++c)
        *(float4*)&po[(pb + qq) * HD + (g << 4) + (c << 2)] =
            make_float4(acc[qq][(c << 2)], acc[qq][(c << 2) + 1],
                        acc[qq][(c << 2) + 2], acc[qq][(c << 2) + 3]);
  }
  if (lane == 0) {
#pragma unroll
    for (int qq = 0; qq < 4; ++qq) {
      pm[pb + qq] = m[qq];
      pl[pb + qq] = l[qq];
    }
  }
}

// ---------------------------------------------------------------------------
// Combine KSPLIT partials -> attention output (B,S,H*D) row-major.
// ---------------------------------------------------------------------------
__global__ __launch_bounds__(256) void combine_k(const float* __restrict__ po,
                                                 const float* __restrict__ pm,
                                                 const float* __restrict__ pl,
                                                 float* __restrict__ attn) {
  const int pair = blockIdx.x;
  const int b = pair >> 4, h = pair & 15;
  const int tid = threadIdx.x;
  const int d = tid & 127, gq = tid >> 7;
#pragma unroll
  for (int qi = 0; qi < 8; ++qi) {
    int qq = gq * 8 + qi;
    float mj[KSPLIT], lj[KSPLIT];
    float Mx = -1e30f;
#pragma unroll
    for (int jj = 0; jj < KSPLIT; ++jj) {
      mj[jj] = pm[((size_t)pair * KSPLIT + jj) * SEQ + qq];
      lj[jj] = pl[((size_t)pair * KSPLIT + jj) * SEQ + qq];
      Mx = fmaxf(Mx, mj[jj]);
    }
    float Ls = 0.f, o = 0.f;
#pragma unroll
    for (int jj = 0; jj < KSPLIT; ++jj) {
      float w = __expf(mj[jj] - Mx);
      Ls += lj[jj] * w;
      o += po[(((size_t)pair * KSPLIT + jj) * SEQ + qq) * HD + d] * w;
    }
    attn[(size_t)(b * SEQ + qq) * EMB + h * HD + d] = o / Ls;
  }
}

// ---------------------------------------------------------------------------
extern "C" void kernel_launch(void* const* d_in, const int* in_sizes, int n_in,
                              void* d_out, int out_size, void* d_ws,
                              size_t ws_size, hipStream_t stream) {
  const float* x = (const float*)d_in[0];
  const float* Wq = (const float*)d_in[1];
  const float* Wk = (const float*)d_in[2];
  const float* Wv = (const float*)d_in[3];
  const float* Wo = (const float*)d_in[4];
  const float* bo = (const float*)d_in[5];
  const float* ck = (const float*)d_in[6];
  const float* cv = (const float*)d_in[7];
  const int* sp = (const int*)d_in[8];
  float* out = (float*)d_out;

  float* ws = (float*)d_ws;
  const size_t U = 262144;  // 128*2048 floats
  float* yq = ws;
  float* yk = ws + U * 1;
  float* yv = ws + U * 2;
  float* attn = ws + U * 3;
  float* qkvParts = ws + U * 4;   // 3 mats x 8 parts -> [4,28)
  float* woParts = ws + U * 28;   // 8 parts -> [28,36)
  float* po = ws + U * 36;        // [36,44)
  float* pm = ws + U * 44;
  float* pl = ws + U * 44 + 16384;

  // 1) QKV projection, split-K=8
  gemm_f32<<<dim3(32, 8, 3), 256, 0, stream>>>(x, Wq, Wk, Wv, qkvParts);

  // 2) sum parts + RoPE on q,k
  sum_qkv_rope_k<<<dim3(256), 256, 0, stream>>>(qkvParts, yq, yk, yv);

  // 3) flash-decoding attention partials (LDS-free)
  attn_partial_k<<<dim3(KSPLIT, NH, BATCH), 256, 0, stream>>>(
      yq, yk, yv, ck, cv, sp, po, pm, pl);

  // 4) combine -> attn (row-major)
  combine_k<<<dim3(BATCH * NH), 256, 0, stream>>>(po, pm, pl, attn);

  // 5) output projection, split-K=8
  gemm_f32<<<dim3(32, 8, 1), 256, 0, stream>>>(attn, Wo, Wo, Wo, woParts);

  // 6) sum parts + bias -> out
  sum8_bias_k<<<dim3(256), 256, 0, stream>>>(woParts, bo, out);

  (void)in_sizes; (void)n_in; (void)out_size; (void)ws_size;
}